// Round 5
// baseline (2514.507 us; speedup 1.0000x reference)
//
#include <hip/hip_runtime.h>
#include <math.h>

#define SS 2048
#define BB 64
#define XDIM 64
#define DXF 128
#define HH 256
#define DHH 128

typedef float v2f __attribute__((ext_vector_type(2)));

// tanh(x) = 1 - 2/(exp(2x)+1); __expf -> v_exp_f32, ~1e-6 abs err, saturates correctly.
__device__ __forceinline__ float ftanh(float x) {
    float e = __expf(2.0f * x);
    return 1.0f - 2.0f / (e + 1.0f);
}

template <int CTRL>
__device__ __forceinline__ float dpp_mov_f(float x) {
    return __int_as_float(__builtin_amdgcn_update_dpp(
        0, __float_as_int(x), CTRL, 0xF, 0xF, true));
}
// 16-lane DPP row reduce, prefix style: lane 15 ends with the row sum
#define RED_SHR(s) { s += dpp_mov_f<0x111>(s); s += dpp_mov_f<0x112>(s); \
                     s += dpp_mov_f<0x114>(s); s += dpp_mov_f<0x118>(s); }
// mirror: lane 0 ends with the row sum
#define RED_SHL(s) { s += dpp_mov_f<0x101>(s); s += dpp_mov_f<0x102>(s); \
                     s += dpp_mov_f<0x104>(s); s += dpp_mov_f<0x108>(s); }

// ---------------------------------------------------------------------------
// K1: u[e,i] = bih[i]+bhh[i] + sum_j tanh(bx[j] + sum_m x[e,m]Wx[m,j]) * Wih[i,j]
// 64 rows/block, 256 threads. Register tiles: 4 cols x 4 rows, float4 LDS reads.
// ---------------------------------------------------------------------------
__global__ __launch_bounds__(256) void k1_featu(
    const float* __restrict__ x, const float* __restrict__ Wx,
    const float* __restrict__ bx, const float* __restrict__ Wih,
    const float* __restrict__ bih, const float* __restrict__ bhh,
    float* __restrict__ u)
{
    __shared__ float xs[64][XDIM];   // 16KB
    __shared__ float fs[64][DXF];    // 32KB
    const int tid = threadIdx.x;
    const size_t row0 = (size_t)blockIdx.x * 64;

    for (int v = tid; v < 64 * XDIM; v += 256) {
        int r = v >> 6, m = v & 63;
        xs[r][m] = x[(row0 + r) * XDIM + m];
    }
    __syncthreads();

    // stage 2: fs = tanh(xs @ Wx + bx). cols: cq+32j; rows: 8ru..8ru+7
    {
        const int cq = tid & 31;
        const int ru = tid >> 5;
        v2f aA[2][4], aB[2][4];
        #pragma unroll
        for (int g = 0; g < 2; ++g)
            #pragma unroll
            for (int i = 0; i < 4; ++i) { aA[g][i] = (v2f)0.f; aB[g][i] = (v2f)0.f; }

        #pragma unroll
        for (int kc = 0; kc < 4; ++kc) {          // K=64, KC=16
            v2f wA[16], wB[16];
            #pragma unroll
            for (int k = 0; k < 16; ++k) {
                const float* wp = Wx + (kc * 16 + k) * DXF + cq;
                wA[k] = (v2f){wp[0],  wp[32]};
                wB[k] = (v2f){wp[64], wp[96]};
            }
            #pragma unroll
            for (int g = 0; g < 2; ++g) {
                const int rb = 8 * ru + 4 * g;
                #pragma unroll
                for (int k4 = 0; k4 < 4; ++k4) {
                    float4 xv[4];
                    #pragma unroll
                    for (int i = 0; i < 4; ++i)
                        xv[i] = *(const float4*)&xs[rb + i][kc * 16 + 4 * k4];
                    #pragma unroll
                    for (int i = 0; i < 4; ++i) {
                        #pragma unroll
                        for (int e = 0; e < 4; ++e) {
                            const float xe = (e == 0) ? xv[i].x : (e == 1) ? xv[i].y
                                           : (e == 2) ? xv[i].z : xv[i].w;
                            const v2f xb = (v2f){xe, xe};
                            aA[g][i] += wA[4 * k4 + e] * xb;
                            aB[g][i] += wB[4 * k4 + e] * xb;
                        }
                    }
                }
            }
        }
        const float b0 = bx[cq], b1 = bx[cq + 32], b2 = bx[cq + 64], b3 = bx[cq + 96];
        #pragma unroll
        for (int g = 0; g < 2; ++g)
            #pragma unroll
            for (int i = 0; i < 4; ++i) {
                const int r = 8 * ru + 4 * g + i;
                fs[r][cq]      = ftanh(aA[g][i].x + b0);
                fs[r][cq + 32] = ftanh(aA[g][i].y + b1);
                fs[r][cq + 64] = ftanh(aB[g][i].x + b2);
                fs[r][cq + 96] = ftanh(aB[g][i].y + b3);
            }
    }
    __syncthreads();

    // stage 3: u = fs @ Wih^T + bih + bhh. cols q4+64j; rows 16rq..16rq+15
    {
        const int q4 = tid & 63;
        const int rq = tid >> 6;
        v2f aA[4][4], aB[4][4];
        #pragma unroll
        for (int g = 0; g < 4; ++g)
            #pragma unroll
            for (int i = 0; i < 4; ++i) { aA[g][i] = (v2f)0.f; aB[g][i] = (v2f)0.f; }

        #pragma unroll
        for (int kc = 0; kc < 8; ++kc) {          // K=128, KC=16
            v2f wA[16], wB[16];
            #pragma unroll
            for (int k4 = 0; k4 < 4; ++k4) {
                const float4 w0 = *(const float4*)(Wih + (size_t)(q4      ) * DXF + kc * 16 + 4 * k4);
                const float4 w1 = *(const float4*)(Wih + (size_t)(q4 +  64) * DXF + kc * 16 + 4 * k4);
                const float4 w2 = *(const float4*)(Wih + (size_t)(q4 + 128) * DXF + kc * 16 + 4 * k4);
                const float4 w3 = *(const float4*)(Wih + (size_t)(q4 + 192) * DXF + kc * 16 + 4 * k4);
                wA[4 * k4 + 0] = (v2f){w0.x, w1.x}; wA[4 * k4 + 1] = (v2f){w0.y, w1.y};
                wA[4 * k4 + 2] = (v2f){w0.z, w1.z}; wA[4 * k4 + 3] = (v2f){w0.w, w1.w};
                wB[4 * k4 + 0] = (v2f){w2.x, w3.x}; wB[4 * k4 + 1] = (v2f){w2.y, w3.y};
                wB[4 * k4 + 2] = (v2f){w2.z, w3.z}; wB[4 * k4 + 3] = (v2f){w2.w, w3.w};
            }
            #pragma unroll
            for (int g = 0; g < 4; ++g) {
                const int rb = 16 * rq + 4 * g;
                #pragma unroll
                for (int k4 = 0; k4 < 4; ++k4) {
                    float4 fv[4];
                    #pragma unroll
                    for (int i = 0; i < 4; ++i)
                        fv[i] = *(const float4*)&fs[rb + i][kc * 16 + 4 * k4];
                    #pragma unroll
                    for (int i = 0; i < 4; ++i) {
                        #pragma unroll
                        for (int e = 0; e < 4; ++e) {
                            const float fe = (e == 0) ? fv[i].x : (e == 1) ? fv[i].y
                                           : (e == 2) ? fv[i].z : fv[i].w;
                            const v2f fb = (v2f){fe, fe};
                            aA[g][i] += wA[4 * k4 + e] * fb;
                            aB[g][i] += wB[4 * k4 + e] * fb;
                        }
                    }
                }
            }
        }
        const float b0 = bih[q4]       + bhh[q4];
        const float b1 = bih[q4 + 64]  + bhh[q4 + 64];
        const float b2 = bih[q4 + 128] + bhh[q4 + 128];
        const float b3 = bih[q4 + 192] + bhh[q4 + 192];
        #pragma unroll
        for (int g = 0; g < 4; ++g)
            #pragma unroll
            for (int i = 0; i < 4; ++i) {
                const size_t row = row0 + 16 * rq + 4 * g + i;
                u[row * HH + q4]       = aA[g][i].x + b0;
                u[row * HH + q4 + 64]  = aA[g][i].y + b1;
                u[row * HH + q4 + 128] = aB[g][i].x + b2;
                u[row * HH + q4 + 192] = aB[g][i].y + b3;
            }
    }
}

// ---------------------------------------------------------------------------
// K2: sequential recurrence. One block of 1024 threads per batch element.
// Thread (rg = tid>>4, c = tid&15): rows 4rg..4rg+3, k-chunk [16c, 16c+16).
// Per-thread weights = 64 floats (32 v2f), PINNED via asm volatile identity:
// asm results are not rematerializable, so the RA cannot re-stream the Whh
// loads into the t-loop (the R1-R4 disease: VGPR_Count 48-92, weights
// re-fetched from L1/L2 every step, ~1800 cyc/step). h reads: 4 ds_read_b128
// per thread, (c>>1)-swizzled -> 2-way bank conflicts only (free, m136).
// 4-stage DPP16 reduce; lane 15 updates rows 4rg..4rg+1, lane 0 rows +2,+3.
// ---------------------------------------------------------------------------
__global__ __launch_bounds__(1024, 4) void k2_rnn(
    const float* __restrict__ u, const float* __restrict__ Whh,
    const float* __restrict__ sigmas, float* __restrict__ hist)
{
    __shared__ float hbuf[2][HH];
    const int tid = threadIdx.x;
    const int b = blockIdx.x;
    const int c = tid & 15;           // k-chunk lane
    const int rg = tid >> 4;          // 0..63 row-quad
    const int sw = c >> 1;            // swizzle phase

    // weights: w2[r][2j],[2j+1] = Whh[4rg+r][16c + 4*((j+sw)&3) + {0..3}]
    v2f w2[4][8];
    #pragma unroll
    for (int r = 0; r < 4; ++r) {
        const float* wrow = Whh + (size_t)(4 * rg + r) * HH + 16 * c;
        #pragma unroll
        for (int j = 0; j < 4; ++j) {
            const int m = (j + sw) & 3;
            const float4 wv = *(const float4*)(wrow + 4 * m);
            w2[r][2 * j]     = (v2f){wv.x, wv.y};
            w2[r][2 * j + 1] = (v2f){wv.z, wv.w};
        }
    }
    // Pin the 32 v2f weight values in VGPRs (non-rematerializable asm results).
    #pragma unroll
    for (int r = 0; r < 4; ++r)
        asm volatile("" : "+v"(w2[r][0]), "+v"(w2[r][1]), "+v"(w2[r][2]),
                          "+v"(w2[r][3]), "+v"(w2[r][4]), "+v"(w2[r][5]),
                          "+v"(w2[r][6]), "+v"(w2[r][7]));

    const bool updHi = (c == 15);     // owns rows 4rg, 4rg+1   (RED_SHR)
    const bool updLo = (c == 0);      // owns rows 4rg+2, 4rg+3 (RED_SHL)
    const bool upd = updHi || updLo;
    const int r0 = 4 * rg + (updHi ? 0 : 2);   // alpha idx of r0 = 0 or 2

    v2f alpha2;
    alpha2.x = 1.f / (1.f + __expf(-sigmas[updHi ? 0 : 2]));
    alpha2.y = 1.f / (1.f + __expf(-sigmas[updHi ? 1 : 3]));

    if (tid < HH) hbuf[0][tid] = 0.0f;

    v2f ucur = (v2f)0.f;
    if (upd) ucur = *(const v2f*)&u[(size_t)b * HH + r0];
    __syncthreads();

    for (int t = 0; t < SS; ++t) {
        const int cur = t & 1;
        const int nxt = cur ^ 1;
        const size_t base = ((size_t)t * BB + b) * HH;

        v2f unext = ucur;
        if (upd) {
            const int tn = (t + 1 < SS) ? (t + 1) : t;
            unext = *(const v2f*)&u[((size_t)tn * BB + b) * HH + r0];
        }

        v2f a0 = (v2f)0.f, a1 = (v2f)0.f, a2 = (v2f)0.f, a3 = (v2f)0.f;
        const float4* hp = (const float4*)&hbuf[cur][16 * c];
        #pragma unroll
        for (int j = 0; j < 4; ++j) {
            const float4 h4 = hp[(j + sw) & 3];
            const v2f hA = (v2f){h4.x, h4.y};
            const v2f hB = (v2f){h4.z, h4.w};
            a0 += w2[0][2 * j] * hA; a0 += w2[0][2 * j + 1] * hB;
            a1 += w2[1][2 * j] * hA; a1 += w2[1][2 * j + 1] * hB;
            a2 += w2[2][2 * j] * hA; a2 += w2[2][2 * j + 1] * hB;
            a3 += w2[3][2 * j] * hA; a3 += w2[3][2 * j + 1] * hB;
        }
        float s0 = a0.x + a0.y, s1 = a1.x + a1.y;
        float s2 = a2.x + a2.y, s3 = a3.x + a3.y;
        RED_SHR(s0) RED_SHR(s1)       // lane 15: rows 4rg, 4rg+1
        RED_SHL(s2) RED_SHL(s3)       // lane 0 : rows 4rg+2, 4rg+3

        if (upd) {
            v2f sv = updHi ? (v2f){s0, s1} : (v2f){s2, s3};
            sv += ucur;
            const v2f hold = *(const v2f*)&hbuf[cur][r0];
            *(v2f*)&hist[base + r0] = hold;       // pre-update h -> y[t]
            v2f hnew;
            hnew.x = hold.x + alpha2.x * (ftanh(sv.x) - hold.x);
            hnew.y = hold.y + alpha2.y * (ftanh(sv.y) - hold.y);
            *(v2f*)&hbuf[nxt][r0] = hnew;
            ucur = unext;
        }
        __syncthreads();
    }
}

// ---------------------------------------------------------------------------
// K3: y[e,o] = bout[o] + sum_k tanh(bhx[k] + sum_i hist[e,i]Whx[i,k]) * Wout[k,o]
// 32 rows/block, 256 threads. Same register-tiling scheme.
// ---------------------------------------------------------------------------
__global__ __launch_bounds__(256) void k3_y(
    const float* __restrict__ hist, const float* __restrict__ Whx,
    const float* __restrict__ bhx, const float* __restrict__ Wout,
    const float* __restrict__ bout, float* __restrict__ y)
{
    __shared__ float hs[32][HH];    // 32KB
    __shared__ float gs[32][DHH];   // 16KB
    const int tid = threadIdx.x;
    const size_t row0 = (size_t)blockIdx.x * 32;

    for (int v = tid; v < 32 * HH; v += 256) {
        int r = v >> 8, i = v & 255;
        hs[r][i] = hist[(row0 + r) * HH + i];
    }
    __syncthreads();

    // stage A: gs = tanh(hs @ Whx + bhx). cols aq+32j; rows 4ru..4ru+3. K=256
    {
        const int aq = tid & 31;
        const int ru = tid >> 5;
        v2f aA[4], aB[4];
        #pragma unroll
        for (int i = 0; i < 4; ++i) { aA[i] = (v2f)0.f; aB[i] = (v2f)0.f; }

        #pragma unroll
        for (int kc = 0; kc < 16; ++kc) {   // KC=16
            v2f wA[16], wB[16];
            #pragma unroll
            for (int k = 0; k < 16; ++k) {
                const float* wp = Whx + (size_t)(kc * 16 + k) * DHH + aq;
                wA[k] = (v2f){wp[0],  wp[32]};
                wB[k] = (v2f){wp[64], wp[96]};
            }
            #pragma unroll
            for (int k4 = 0; k4 < 4; ++k4) {
                float4 hv[4];
                #pragma unroll
                for (int i = 0; i < 4; ++i)
                    hv[i] = *(const float4*)&hs[4 * ru + i][kc * 16 + 4 * k4];
                #pragma unroll
                for (int i = 0; i < 4; ++i) {
                    #pragma unroll
                    for (int e = 0; e < 4; ++e) {
                        const float he = (e == 0) ? hv[i].x : (e == 1) ? hv[i].y
                                       : (e == 2) ? hv[i].z : hv[i].w;
                        const v2f hb = (v2f){he, he};
                        aA[i] += wA[4 * k4 + e] * hb;
                        aB[i] += wB[4 * k4 + e] * hb;
                    }
                }
            }
        }
        const float b0 = bhx[aq], b1 = bhx[aq + 32], b2 = bhx[aq + 64], b3 = bhx[aq + 96];
        #pragma unroll
        for (int i = 0; i < 4; ++i) {
            const int r = 4 * ru + i;
            gs[r][aq]      = ftanh(aA[i].x + b0);
            gs[r][aq + 32] = ftanh(aA[i].y + b1);
            gs[r][aq + 64] = ftanh(aB[i].x + b2);
            gs[r][aq + 96] = ftanh(aB[i].y + b3);
        }
    }
    __syncthreads();

    // stage B: y = gs @ Wout + bout. cols o2, o2+32; rows 4ru..4ru+3. K=128
    {
        const int o2 = tid & 31;
        const int ru = tid >> 5;
        v2f acc[4];
        #pragma unroll
        for (int i = 0; i < 4; ++i) acc[i] = (v2f)0.f;

        #pragma unroll
        for (int kc = 0; kc < 2; ++kc) {    // KC=64
            v2f w[64];
            #pragma unroll
            for (int k = 0; k < 64; ++k) {
                const float* wp = Wout + (size_t)(kc * 64 + k) * XDIM + o2;
                w[k] = (v2f){wp[0], wp[32]};
            }
            #pragma unroll
            for (int k4 = 0; k4 < 16; ++k4) {
                float4 gv[4];
                #pragma unroll
                for (int i = 0; i < 4; ++i)
                    gv[i] = *(const float4*)&gs[4 * ru + i][kc * 64 + 4 * k4];
                #pragma unroll
                for (int i = 0; i < 4; ++i) {
                    #pragma unroll
                    for (int e = 0; e < 4; ++e) {
                        const float ge = (e == 0) ? gv[i].x : (e == 1) ? gv[i].y
                                       : (e == 2) ? gv[i].z : gv[i].w;
                        acc[i] += w[4 * k4 + e] * (v2f){ge, ge};
                    }
                }
            }
        }
        const float b0 = bout[o2], b1 = bout[o2 + 32];
        #pragma unroll
        for (int i = 0; i < 4; ++i) {
            const size_t row = row0 + 4 * ru + i;
            y[row * XDIM + o2]      = acc[i].x + b0;
            y[row * XDIM + o2 + 32] = acc[i].y + b1;
        }
    }
}

extern "C" void kernel_launch(void* const* d_in, const int* in_sizes, int n_in,
                              void* d_out, int out_size, void* d_ws, size_t ws_size,
                              hipStream_t stream) {
    const float* x      = (const float*)d_in[0];
    const float* Wx     = (const float*)d_in[1];
    const float* bx     = (const float*)d_in[2];
    const float* Wih    = (const float*)d_in[3];
    const float* bih    = (const float*)d_in[4];
    const float* Whh    = (const float*)d_in[5];
    const float* bhh    = (const float*)d_in[6];
    const float* Whx    = (const float*)d_in[7];
    const float* bhx    = (const float*)d_in[8];
    const float* Wout   = (const float*)d_in[9];
    const float* bout   = (const float*)d_in[10];
    const float* sigmas = (const float*)d_in[11];
    float* y = (float*)d_out;

    float* u    = (float*)d_ws;                   // S*B*H floats = 128 MB
    float* hist = u + (size_t)SS * BB * HH;       // S*B*H floats = 128 MB

    k1_featu<<<(SS * BB) / 64, 256, 0, stream>>>(x, Wx, bx, Wih, bih, bhh, u);
    k2_rnn<<<BB, 1024, 0, stream>>>(u, Whh, sigmas, hist);
    k3_y<<<(SS * BB) / 32, 256, 0, stream>>>(hist, Whx, bhx, Wout, bout, y);
}

// Round 6
// 2008.084 us; speedup vs baseline: 1.2522x; 1.2522x over previous
//
#include <hip/hip_runtime.h>
#include <math.h>

#define SS 2048
#define BB 64
#define XDIM 64
#define DXF 128
#define HH 256
#define DHH 128

typedef float v2f __attribute__((ext_vector_type(2)));

// tanh(x) = 1 - 2/(exp(2x)+1); __expf -> v_exp_f32, ~1e-6 abs err, saturates correctly.
__device__ __forceinline__ float ftanh(float x) {
    float e = __expf(2.0f * x);
    return 1.0f - 2.0f / (e + 1.0f);
}

template <int CTRL>
__device__ __forceinline__ float dpp_mov_f(float x) {
    return __int_as_float(__builtin_amdgcn_update_dpp(
        0, __float_as_int(x), CTRL, 0xF, 0xF, true));
}
// 8-lane group reduce via DPP row_shr: lane 7 (and 15) of each 16-lane row
// ends with the sum of its 8-lane half.
#define RED8_SHR(s) { s += dpp_mov_f<0x111>(s); s += dpp_mov_f<0x112>(s); \
                      s += dpp_mov_f<0x114>(s); }
// mirror: lane 0 (and 8) gets its half's sum
#define RED8_SHL(s) { s += dpp_mov_f<0x101>(s); s += dpp_mov_f<0x102>(s); \
                      s += dpp_mov_f<0x104>(s); }

// ---------------------------------------------------------------------------
// K1: u[e,i] = bih[i]+bhh[i] + sum_j tanh(bx[j] + sum_m x[e,m]Wx[m,j]) * Wih[i,j]
// 64 rows/block, 256 threads. Register tiles: 4 cols x 4 rows, float4 LDS reads.
// ---------------------------------------------------------------------------
__global__ __launch_bounds__(256) void k1_featu(
    const float* __restrict__ x, const float* __restrict__ Wx,
    const float* __restrict__ bx, const float* __restrict__ Wih,
    const float* __restrict__ bih, const float* __restrict__ bhh,
    float* __restrict__ u)
{
    __shared__ float xs[64][XDIM];   // 16KB
    __shared__ float fs[64][DXF];    // 32KB
    const int tid = threadIdx.x;
    const size_t row0 = (size_t)blockIdx.x * 64;

    for (int v = tid; v < 64 * XDIM; v += 256) {
        int r = v >> 6, m = v & 63;
        xs[r][m] = x[(row0 + r) * XDIM + m];
    }
    __syncthreads();

    // stage 2: fs = tanh(xs @ Wx + bx). cols: cq+32j; rows: 8ru..8ru+7
    {
        const int cq = tid & 31;
        const int ru = tid >> 5;
        v2f aA[2][4], aB[2][4];
        #pragma unroll
        for (int g = 0; g < 2; ++g)
            #pragma unroll
            for (int i = 0; i < 4; ++i) { aA[g][i] = (v2f)0.f; aB[g][i] = (v2f)0.f; }

        #pragma unroll
        for (int kc = 0; kc < 4; ++kc) {          // K=64, KC=16
            v2f wA[16], wB[16];
            #pragma unroll
            for (int k = 0; k < 16; ++k) {
                const float* wp = Wx + (kc * 16 + k) * DXF + cq;
                wA[k] = (v2f){wp[0],  wp[32]};
                wB[k] = (v2f){wp[64], wp[96]};
            }
            #pragma unroll
            for (int g = 0; g < 2; ++g) {
                const int rb = 8 * ru + 4 * g;
                #pragma unroll
                for (int k4 = 0; k4 < 4; ++k4) {
                    float4 xv[4];
                    #pragma unroll
                    for (int i = 0; i < 4; ++i)
                        xv[i] = *(const float4*)&xs[rb + i][kc * 16 + 4 * k4];
                    #pragma unroll
                    for (int i = 0; i < 4; ++i) {
                        #pragma unroll
                        for (int e = 0; e < 4; ++e) {
                            const float xe = (e == 0) ? xv[i].x : (e == 1) ? xv[i].y
                                           : (e == 2) ? xv[i].z : xv[i].w;
                            const v2f xb = (v2f){xe, xe};
                            aA[g][i] += wA[4 * k4 + e] * xb;
                            aB[g][i] += wB[4 * k4 + e] * xb;
                        }
                    }
                }
            }
        }
        const float b0 = bx[cq], b1 = bx[cq + 32], b2 = bx[cq + 64], b3 = bx[cq + 96];
        #pragma unroll
        for (int g = 0; g < 2; ++g)
            #pragma unroll
            for (int i = 0; i < 4; ++i) {
                const int r = 8 * ru + 4 * g + i;
                fs[r][cq]      = ftanh(aA[g][i].x + b0);
                fs[r][cq + 32] = ftanh(aA[g][i].y + b1);
                fs[r][cq + 64] = ftanh(aB[g][i].x + b2);
                fs[r][cq + 96] = ftanh(aB[g][i].y + b3);
            }
    }
    __syncthreads();

    // stage 3: u = fs @ Wih^T + bih + bhh. cols q4+64j; rows 16rq..16rq+15
    {
        const int q4 = tid & 63;
        const int rq = tid >> 6;
        v2f aA[4][4], aB[4][4];
        #pragma unroll
        for (int g = 0; g < 4; ++g)
            #pragma unroll
            for (int i = 0; i < 4; ++i) { aA[g][i] = (v2f)0.f; aB[g][i] = (v2f)0.f; }

        #pragma unroll
        for (int kc = 0; kc < 8; ++kc) {          // K=128, KC=16
            v2f wA[16], wB[16];
            #pragma unroll
            for (int k4 = 0; k4 < 4; ++k4) {
                const float4 w0 = *(const float4*)(Wih + (size_t)(q4      ) * DXF + kc * 16 + 4 * k4);
                const float4 w1 = *(const float4*)(Wih + (size_t)(q4 +  64) * DXF + kc * 16 + 4 * k4);
                const float4 w2 = *(const float4*)(Wih + (size_t)(q4 + 128) * DXF + kc * 16 + 4 * k4);
                const float4 w3 = *(const float4*)(Wih + (size_t)(q4 + 192) * DXF + kc * 16 + 4 * k4);
                wA[4 * k4 + 0] = (v2f){w0.x, w1.x}; wA[4 * k4 + 1] = (v2f){w0.y, w1.y};
                wA[4 * k4 + 2] = (v2f){w0.z, w1.z}; wA[4 * k4 + 3] = (v2f){w0.w, w1.w};
                wB[4 * k4 + 0] = (v2f){w2.x, w3.x}; wB[4 * k4 + 1] = (v2f){w2.y, w3.y};
                wB[4 * k4 + 2] = (v2f){w2.z, w3.z}; wB[4 * k4 + 3] = (v2f){w2.w, w3.w};
            }
            #pragma unroll
            for (int g = 0; g < 4; ++g) {
                const int rb = 16 * rq + 4 * g;
                #pragma unroll
                for (int k4 = 0; k4 < 4; ++k4) {
                    float4 fv[4];
                    #pragma unroll
                    for (int i = 0; i < 4; ++i)
                        fv[i] = *(const float4*)&fs[rb + i][kc * 16 + 4 * k4];
                    #pragma unroll
                    for (int i = 0; i < 4; ++i) {
                        #pragma unroll
                        for (int e = 0; e < 4; ++e) {
                            const float fe = (e == 0) ? fv[i].x : (e == 1) ? fv[i].y
                                           : (e == 2) ? fv[i].z : fv[i].w;
                            const v2f fb = (v2f){fe, fe};
                            aA[g][i] += wA[4 * k4 + e] * fb;
                            aB[g][i] += wB[4 * k4 + e] * fb;
                        }
                    }
                }
            }
        }
        const float b0 = bih[q4]       + bhh[q4];
        const float b1 = bih[q4 + 64]  + bhh[q4 + 64];
        const float b2 = bih[q4 + 128] + bhh[q4 + 128];
        const float b3 = bih[q4 + 192] + bhh[q4 + 192];
        #pragma unroll
        for (int g = 0; g < 4; ++g)
            #pragma unroll
            for (int i = 0; i < 4; ++i) {
                const size_t row = row0 + 16 * rq + 4 * g + i;
                u[row * HH + q4]       = aA[g][i].x + b0;
                u[row * HH + q4 + 64]  = aA[g][i].y + b1;
                u[row * HH + q4 + 128] = aB[g][i].x + b2;
                u[row * HH + q4 + 192] = aB[g][i].y + b3;
            }
    }
}

// ---------------------------------------------------------------------------
// K2: sequential recurrence. One block of 1024 threads per batch element.
// Thread (rg = tid>>3, c = tid&7): rows {2rg, 2rg+1}, k-chunk [32c, 32c+32).
//
// THE FIX (R5 post-mortem): __launch_bounds__'s 2nd arg is only a MINIMUM
// waves/EU; the backend's default heuristic targets MAX occupancy (8-10
// waves/EU => 48-64 VGPR budget) and under that budget it remats (R2-R4) or
// scratch-spills (R5) the per-thread weight array every t-iteration —
// VGPR_Count 48/52/92 across five rounds. amdgpu_waves_per_eu(4,4) pins the
// range, fixing the budget at 512/4 = 128 VGPRs; the ~95-VGPR kernel fits and
// the 64 weight floats finally stay resident. Grid = 64 blocks => 1 block/CU,
// so capping occupancy at 4 waves/EU costs nothing.
//
// LDS h reads: 8x ds_read_b128, swizzled (j+c)&7 => 8 distinct float4 addrs
// covering all 32 banks once, 8-way broadcast across rg groups — measured
// ZERO conflicts in R4. 3-stage DPP reduce over the 8 c-lanes.
// ---------------------------------------------------------------------------
__global__ __launch_bounds__(1024)
__attribute__((amdgpu_waves_per_eu(4, 4)))
void k2_rnn(
    const float* __restrict__ u, const float* __restrict__ Whh,
    const float* __restrict__ sigmas, float* __restrict__ hist)
{
    __shared__ float hbuf[2][HH];
    const int tid = threadIdx.x;
    const int b = blockIdx.x;
    const int c = tid & 7;            // k-chunk
    const int rg = tid >> 3;          // 0..127 row-pair group

    // weights: w2[r][2j],[2j+1] = Whh[2rg+r][32c + 4*((j+c)&7) + {0..3}]
    v2f w2[2][16];
    #pragma unroll
    for (int r = 0; r < 2; ++r) {
        const float* wrow = Whh + (size_t)(2 * rg + r) * HH + 32 * c;
        #pragma unroll
        for (int j = 0; j < 8; ++j) {
            const int kk = 4 * ((j + c) & 7);
            const float4 wv = *(const float4*)(wrow + kk);
            w2[r][2 * j]     = (v2f){wv.x, wv.y};
            w2[r][2 * j + 1] = (v2f){wv.z, wv.w};
        }
    }
    // Pin: asm results are non-rematerializable, so with the (4,4) budget the
    // RA keeps all 32 v2f live in VGPRs across the whole t-loop.
    #pragma unroll
    for (int r = 0; r < 2; ++r) {
        asm volatile("" : "+v"(w2[r][0]),  "+v"(w2[r][1]),  "+v"(w2[r][2]),
                          "+v"(w2[r][3]),  "+v"(w2[r][4]),  "+v"(w2[r][5]),
                          "+v"(w2[r][6]),  "+v"(w2[r][7]),  "+v"(w2[r][8]),
                          "+v"(w2[r][9]),  "+v"(w2[r][10]), "+v"(w2[r][11]),
                          "+v"(w2[r][12]), "+v"(w2[r][13]), "+v"(w2[r][14]),
                          "+v"(w2[r][15]));
    }

    const bool updHi = (c == 7);      // owns row 2rg   (sum via RED8_SHR)
    const bool updLo = (c == 0);      // owns row 2rg+1 (sum via RED8_SHL)
    const bool upd = updHi || updLo;
    const int myrow = 2 * rg + (updHi ? 0 : 1);

    const float alpha = 1.f / (1.f + __expf(-sigmas[myrow & 3]));

    if (tid < HH) hbuf[0][tid] = 0.0f;

    float ucur = 0.f;
    if (upd) ucur = u[(size_t)b * HH + myrow];
    __syncthreads();

    for (int t = 0; t < SS; ++t) {
        const int cur = t & 1;
        const int nxt = cur ^ 1;
        const size_t base = ((size_t)t * BB + b) * HH;

        float unext = ucur;
        if (upd) {
            const int tn = (t + 1 < SS) ? (t + 1) : t;
            unext = u[((size_t)tn * BB + b) * HH + myrow];
        }

        v2f a0 = (v2f)0.f, a1 = (v2f)0.f;
        const float4* h4p = (const float4*)&hbuf[cur][32 * c];
        #pragma unroll
        for (int j = 0; j < 8; ++j) {
            const float4 h4 = h4p[(j + c) & 7];
            const v2f hA = (v2f){h4.x, h4.y};
            const v2f hB = (v2f){h4.z, h4.w};
            a0 += w2[0][2 * j] * hA; a0 += w2[0][2 * j + 1] * hB;
            a1 += w2[1][2 * j] * hA; a1 += w2[1][2 * j + 1] * hB;
        }
        float s0 = a0.x + a0.y;
        float s1 = a1.x + a1.y;
        RED8_SHR(s0)                  // lane c=7 gets row 2rg sum
        RED8_SHL(s1)                  // lane c=0 gets row 2rg+1 sum

        if (upd) {
            const float s = (updHi ? s0 : s1) + ucur;
            const float hold = hbuf[cur][myrow];
            hist[base + myrow] = hold;            // pre-update h -> y[t]
            hbuf[nxt][myrow] = hold + alpha * (ftanh(s) - hold);
            ucur = unext;
        }
        __syncthreads();
    }
}

// ---------------------------------------------------------------------------
// K3: y[e,o] = bout[o] + sum_k tanh(bhx[k] + sum_i hist[e,i]Whx[i,k]) * Wout[k,o]
// 32 rows/block, 256 threads. Same register-tiling scheme.
// ---------------------------------------------------------------------------
__global__ __launch_bounds__(256) void k3_y(
    const float* __restrict__ hist, const float* __restrict__ Whx,
    const float* __restrict__ bhx, const float* __restrict__ Wout,
    const float* __restrict__ bout, float* __restrict__ y)
{
    __shared__ float hs[32][HH];    // 32KB
    __shared__ float gs[32][DHH];   // 16KB
    const int tid = threadIdx.x;
    const size_t row0 = (size_t)blockIdx.x * 32;

    for (int v = tid; v < 32 * HH; v += 256) {
        int r = v >> 8, i = v & 255;
        hs[r][i] = hist[(row0 + r) * HH + i];
    }
    __syncthreads();

    // stage A: gs = tanh(hs @ Whx + bhx). cols aq+32j; rows 4ru..4ru+3. K=256
    {
        const int aq = tid & 31;
        const int ru = tid >> 5;
        v2f aA[4], aB[4];
        #pragma unroll
        for (int i = 0; i < 4; ++i) { aA[i] = (v2f)0.f; aB[i] = (v2f)0.f; }

        #pragma unroll
        for (int kc = 0; kc < 16; ++kc) {   // KC=16
            v2f wA[16], wB[16];
            #pragma unroll
            for (int k = 0; k < 16; ++k) {
                const float* wp = Whx + (size_t)(kc * 16 + k) * DHH + aq;
                wA[k] = (v2f){wp[0],  wp[32]};
                wB[k] = (v2f){wp[64], wp[96]};
            }
            #pragma unroll
            for (int k4 = 0; k4 < 4; ++k4) {
                float4 hv[4];
                #pragma unroll
                for (int i = 0; i < 4; ++i)
                    hv[i] = *(const float4*)&hs[4 * ru + i][kc * 16 + 4 * k4];
                #pragma unroll
                for (int i = 0; i < 4; ++i) {
                    #pragma unroll
                    for (int e = 0; e < 4; ++e) {
                        const float he = (e == 0) ? hv[i].x : (e == 1) ? hv[i].y
                                       : (e == 2) ? hv[i].z : hv[i].w;
                        const v2f hb = (v2f){he, he};
                        aA[i] += wA[4 * k4 + e] * hb;
                        aB[i] += wB[4 * k4 + e] * hb;
                    }
                }
            }
        }
        const float b0 = bhx[aq], b1 = bhx[aq + 32], b2 = bhx[aq + 64], b3 = bhx[aq + 96];
        #pragma unroll
        for (int i = 0; i < 4; ++i) {
            const int r = 4 * ru + i;
            gs[r][aq]      = ftanh(aA[i].x + b0);
            gs[r][aq + 32] = ftanh(aA[i].y + b1);
            gs[r][aq + 64] = ftanh(aB[i].x + b2);
            gs[r][aq + 96] = ftanh(aB[i].y + b3);
        }
    }
    __syncthreads();

    // stage B: y = gs @ Wout + bout. cols o2, o2+32; rows 4ru..4ru+3. K=128
    {
        const int o2 = tid & 31;
        const int ru = tid >> 5;
        v2f acc[4];
        #pragma unroll
        for (int i = 0; i < 4; ++i) acc[i] = (v2f)0.f;

        #pragma unroll
        for (int kc = 0; kc < 2; ++kc) {    // KC=64
            v2f w[64];
            #pragma unroll
            for (int k = 0; k < 64; ++k) {
                const float* wp = Wout + (size_t)(kc * 64 + k) * XDIM + o2;
                w[k] = (v2f){wp[0], wp[32]};
            }
            #pragma unroll
            for (int k4 = 0; k4 < 16; ++k4) {
                float4 gv[4];
                #pragma unroll
                for (int i = 0; i < 4; ++i)
                    gv[i] = *(const float4*)&gs[4 * ru + i][kc * 64 + 4 * k4];
                #pragma unroll
                for (int i = 0; i < 4; ++i) {
                    #pragma unroll
                    for (int e = 0; e < 4; ++e) {
                        const float ge = (e == 0) ? gv[i].x : (e == 1) ? gv[i].y
                                       : (e == 2) ? gv[i].z : gv[i].w;
                        acc[i] += w[4 * k4 + e] * (v2f){ge, ge};
                    }
                }
            }
        }
        const float b0 = bout[o2], b1 = bout[o2 + 32];
        #pragma unroll
        for (int i = 0; i < 4; ++i) {
            const size_t row = row0 + 4 * ru + i;
            y[row * XDIM + o2]      = acc[i].x + b0;
            y[row * XDIM + o2 + 32] = acc[i].y + b1;
        }
    }
}

extern "C" void kernel_launch(void* const* d_in, const int* in_sizes, int n_in,
                              void* d_out, int out_size, void* d_ws, size_t ws_size,
                              hipStream_t stream) {
    const float* x      = (const float*)d_in[0];
    const float* Wx     = (const float*)d_in[1];
    const float* bx     = (const float*)d_in[2];
    const float* Wih    = (const float*)d_in[3];
    const float* bih    = (const float*)d_in[4];
    const float* Whh    = (const float*)d_in[5];
    const float* bhh    = (const float*)d_in[6];
    const float* Whx    = (const float*)d_in[7];
    const float* bhx    = (const float*)d_in[8];
    const float* Wout   = (const float*)d_in[9];
    const float* bout   = (const float*)d_in[10];
    const float* sigmas = (const float*)d_in[11];
    float* y = (float*)d_out;

    float* u    = (float*)d_ws;                   // S*B*H floats = 128 MB
    float* hist = u + (size_t)SS * BB * HH;       // S*B*H floats = 128 MB

    k1_featu<<<(SS * BB) / 64, 256, 0, stream>>>(x, Wx, bx, Wih, bih, bhh, u);
    k2_rnn<<<BB, 1024, 0, stream>>>(u, Whh, sigmas, hist);
    k3_y<<<(SS * BB) / 32, 256, 0, stream>>>(hist, Whx, bhx, Wout, bout, y);
}